// Round 3
// baseline (366.170 us; speedup 1.0000x reference)
//
#include <hip/hip_runtime.h>
#include <stdint.h>

#define D_MODEL 1024
#define SEQ 2048
#define NBATCH 4

typedef __attribute__((ext_vector_type(4))) float f32x4;
typedef __attribute__((ext_vector_type(8))) __bf16 bf16x8;
typedef __attribute__((ext_vector_type(4))) unsigned short u16x4;

__device__ __forceinline__ float b2f(unsigned short u) {
    union { unsigned int i; float f; } c; c.i = ((unsigned int)u) << 16; return c.f;
}
// round-to-nearest-even f32 -> bf16 (finite inputs only)
__device__ __forceinline__ unsigned short f2b(float f) {
    union { float f; unsigned int i; } c; c.f = f;
    unsigned int u = c.i;
    u += 0x7FFFu + ((u >> 16) & 1u);
    return (unsigned short)(u >> 16);
}

// fp32 -> bf16 elementwise cast (n elements, 4 per thread)
__global__ __launch_bounds__(256)
void cast_bf16(const float* __restrict__ in, unsigned short* __restrict__ outp, long n)
{
    long i = ((long)blockIdx.x * 256 + threadIdx.x) * 4;
    if (i + 3 < n) {
        f32x4 v = *(const f32x4*)(in + i);
        u16x4 o;
        #pragma unroll
        for (int r = 0; r < 4; ++r) o[r] = f2b(v[r]);
        *(u16x4*)(outp + i) = o;
    }
}

// C[m,n] = sum_k A[m,k] * Bt[n,k]  (+ bias[n]); A,Bt bf16 (ushort), fp32 accumulate.
// A: [M,K] row-major, Bt: [N,K] row-major. M,N multiples of 128, K multiple of 32.
// OutT = ushort (bf16 store) or float (fp32 store, TSTORE==0 only).
// TSTORE==1 (ushort only): transposed per-batch store Ct[b][n][s], b=m>>11, s=m&2047.
template<int TSTORE, bool BIAS, typename OutT>
__global__ __launch_bounds__(256)
void gemm_bt(const unsigned short* __restrict__ A,
             const unsigned short* __restrict__ Bt,
             const float* __restrict__ bias,
             OutT* __restrict__ C,
             int M, int N, int K, long sA, long sB, long sC)
{
    A  += (long)blockIdx.z * sA;
    Bt += (long)blockIdx.z * sB;
    C  += (long)blockIdx.z * sC;

    __shared__ alignas(16) unsigned short As[128 * 32];
    __shared__ alignas(16) unsigned short Bs[128 * 32];

    const int t    = threadIdx.x;
    const int m0   = blockIdx.y * 128;
    const int n0   = blockIdx.x * 128;
    const int srow = t >> 2;          // staging row 0..63 (and +64)
    const int sch  = (t & 3) * 8;     // 16B chunk within 64B row

    const unsigned short* Ag = A  + (long)(m0 + srow) * K + sch;
    const unsigned short* Bg = Bt + (long)(n0 + srow) * K + sch;

    uint4* AsW0 = (uint4*)((char*)As + t * 16);
    uint4* AsW1 = (uint4*)((char*)As + 4096 + t * 16);
    uint4* BsW0 = (uint4*)((char*)Bs + t * 16);
    uint4* BsW1 = (uint4*)((char*)Bs + 4096 + t * 16);

    const int wave = t >> 6;
    const int lane = t & 63;
    const int wm   = (wave >> 1) * 64;   // 2x2 wave grid, 64x64 per wave
    const int wn   = (wave & 1) * 64;
    const int fr   = lane & 15;
    const int quad = lane >> 4;

    f32x4 acc[4][4] = {};

    for (int k0 = 0; k0 < K; k0 += 32) {
        uint4 a0 = *(const uint4*)(Ag + k0);
        uint4 a1 = *(const uint4*)(Ag + 64 * (long)K + k0);
        uint4 b0 = *(const uint4*)(Bg + k0);
        uint4 b1 = *(const uint4*)(Bg + 64 * (long)K + k0);

        __syncthreads();   // previous iter's LDS reads done
        *AsW0 = a0;
        *AsW1 = a1;
        *BsW0 = b0;
        *BsW1 = b1;
        __syncthreads();   // tile fully written

        bf16x8 af[4], bfv[4];
        #pragma unroll
        for (int i = 0; i < 4; ++i)   // A frag: m = fr, k = quad*8 + j
            af[i] = *(const bf16x8*)(As + (wm + i * 16 + fr) * 32 + quad * 8);
        #pragma unroll
        for (int i = 0; i < 4; ++i)   // B frag: n = fr, k = quad*8 + j
            bfv[i] = *(const bf16x8*)(Bs + (wn + i * 16 + fr) * 32 + quad * 8);

        #pragma unroll
        for (int mi = 0; mi < 4; ++mi)
            #pragma unroll
            for (int ni = 0; ni < 4; ++ni)
                acc[mi][ni] = __builtin_amdgcn_mfma_f32_16x16x32_bf16(
                                  af[mi], bfv[ni], acc[mi][ni], 0, 0, 0);
    }

    float bb[4] = {0.f, 0.f, 0.f, 0.f};
    if (BIAS) {
        #pragma unroll
        for (int ni = 0; ni < 4; ++ni)
            bb[ni] = bias[n0 + wn + ni * 16 + fr];
    }

    // C/D layout (HW-verified): col = lane&15, row = quad*4 + reg
    #pragma unroll
    for (int mi = 0; mi < 4; ++mi) {
        const int rowb = m0 + wm + mi * 16 + quad * 4;
        #pragma unroll
        for (int ni = 0; ni < 4; ++ni) {
            const int col = n0 + wn + ni * 16 + fr;
            f32x4 v = acc[mi][ni];
            if constexpr (sizeof(OutT) == 4) {
                #pragma unroll
                for (int r = 0; r < 4; ++r)
                    C[(long)(rowb + r) * N + col] = v[r] + bb[ni];
            } else if constexpr (TSTORE == 0) {
                #pragma unroll
                for (int r = 0; r < 4; ++r)
                    C[(long)(rowb + r) * N + col] = (OutT)f2b(v[r] + bb[ni]);
            } else {
                u16x4 pk;
                #pragma unroll
                for (int r = 0; r < 4; ++r)
                    pk[r] = f2b(v[r] + bb[ni]);
                unsigned short* dst = (unsigned short*)C
                                    + ((long)(rowb >> 11)) * ((long)N * SEQ)
                                    + (long)col * SEQ + (rowb & (SEQ - 1));
                *(u16x4*)dst = pk;   // 4 consecutive s positions, 8B aligned
            }
        }
    }
}

// In-place softmax over rows of 2048 bf16 raw scores, with 1/sqrt(1024) scaling.
__global__ __launch_bounds__(256)
void softmax_inplace(unsigned short* __restrict__ S)
{
    const long row = blockIdx.x;
    unsigned short* s = S + row * SEQ;
    const int t = threadIdx.x;

    u16x4 a = ((const u16x4*)s)[t];
    u16x4 b = ((const u16x4*)s)[t + 256];
    float v[8];
    #pragma unroll
    for (int i = 0; i < 4; ++i) { v[i] = b2f(a[i]); v[4 + i] = b2f(b[i]); }

    float mx = v[0];
    #pragma unroll
    for (int i = 1; i < 8; ++i) mx = fmaxf(mx, v[i]);
    #pragma unroll
    for (int off = 32; off; off >>= 1) mx = fmaxf(mx, __shfl_xor(mx, off));

    __shared__ float red[8];
    const int wv = t >> 6, ln = t & 63;
    if (ln == 0) red[wv] = mx;
    __syncthreads();
    mx = fmaxf(fmaxf(red[0], red[1]), fmaxf(red[2], red[3]));

    const float sc = 0.03125f;  // 1/sqrt(1024)
    float e[8], sum = 0.f;
    #pragma unroll
    for (int i = 0; i < 8; ++i) { e[i] = __expf((v[i] - mx) * sc); sum += e[i]; }
    #pragma unroll
    for (int off = 32; off; off >>= 1) sum += __shfl_xor(sum, off);
    if (ln == 0) red[4 + wv] = sum;   // disjoint slots
    __syncthreads();
    sum = (red[4] + red[5]) + (red[6] + red[7]);
    const float inv = 1.f / sum;

    u16x4 o;
    #pragma unroll
    for (int i = 0; i < 4; ++i) o[i] = f2b(e[i] * inv);
    ((u16x4*)s)[t] = o;
    #pragma unroll
    for (int i = 0; i < 4; ++i) o[i] = f2b(e[4 + i] * inv);
    ((u16x4*)s)[t + 256] = o;
}

// 1024x1024 transpose + fp32->bf16 cast: W[k][n] fp32 -> Wt[n][k] bf16
__global__ __launch_bounds__(256)
void transpose_w(const float* __restrict__ W, unsigned short* __restrict__ Wt)
{
    __shared__ float tile[32][33];
    const int bx = blockIdx.x * 32, by = blockIdx.y * 32;
    const int tx = threadIdx.x & 31, ty = threadIdx.x >> 5;
    #pragma unroll
    for (int i = 0; i < 32; i += 8)
        tile[ty + i][tx] = W[(long)(by + ty + i) * D_MODEL + bx + tx];
    __syncthreads();
    #pragma unroll
    for (int i = 0; i < 32; i += 8)
        Wt[(long)(bx + ty + i) * D_MODEL + by + tx] = f2b(tile[tx][ty + i]);
}

extern "C" void kernel_launch(void* const* d_in, const int* in_sizes, int n_in,
                              void* d_out, int out_size, void* d_ws, size_t ws_size,
                              hipStream_t stream)
{
    const float* x  = (const float*)d_in[0];
    const float* Wq = (const float*)d_in[1];
    const float* bq = (const float*)d_in[2];
    const float* Wk = (const float*)d_in[3];
    const float* bk = (const float*)d_in[4];
    const float* Wv = (const float*)d_in[5];
    const float* bv = (const float*)d_in[6];
    const float* Wo = (const float*)d_in[7];
    const float* bo = (const float*)d_in[8];
    float* out = (float*)d_out;

    char* ws = (char*)d_ws;
    const size_t MB = 1024ull * 1024ull;
    unsigned short* Wqt = (unsigned short*)(ws + 0 * MB);    // 2MB each
    unsigned short* Wkt = (unsigned short*)(ws + 2 * MB);
    unsigned short* Wvt = (unsigned short*)(ws + 4 * MB);
    unsigned short* Wot = (unsigned short*)(ws + 6 * MB);
    unsigned short* xb  = (unsigned short*)(ws + 8 * MB);    // [8192,1024] bf16 = 16MB
    unsigned short* Q   = (unsigned short*)(ws + 24 * MB);   // 16MB
    unsigned short* Kb  = (unsigned short*)(ws + 40 * MB);   // 16MB
    unsigned short* Vt  = (unsigned short*)(ws + 56 * MB);   // [4][1024][2048] = 16MB
    unsigned short* At  = (unsigned short*)(ws + 72 * MB);   // 16MB
    unsigned short* S   = (unsigned short*)(ws + 88 * MB);   // 32MB -> 120MB total

    const dim3 blk(256);
    const long nx = (long)NBATCH * SEQ * D_MODEL;            // 8388608
    cast_bf16<<<dim3((unsigned)(nx / (256 * 4))), blk, 0, stream>>>(x, xb, nx);

    const dim3 tgrid(32, 32);
    transpose_w<<<tgrid, blk, 0, stream>>>(Wq, Wqt);
    transpose_w<<<tgrid, blk, 0, stream>>>(Wk, Wkt);
    transpose_w<<<tgrid, blk, 0, stream>>>(Wv, Wvt);
    transpose_w<<<tgrid, blk, 0, stream>>>(Wo, Wot);

    // Q/K/V projections over all batches (M=8192). V stored transposed per batch.
    gemm_bt<0, true, unsigned short><<<dim3(8, 64, 1), blk, 0, stream>>>(
        xb, Wqt, bq, Q,  8192, 1024, 1024, 0, 0, 0);
    gemm_bt<0, true, unsigned short><<<dim3(8, 64, 1), blk, 0, stream>>>(
        xb, Wkt, bk, Kb, 8192, 1024, 1024, 0, 0, 0);
    gemm_bt<1, true, unsigned short><<<dim3(8, 64, 1), blk, 0, stream>>>(
        xb, Wvt, bv, Vt, 8192, 1024, 1024, 0, 0, 0);

    // scores[b] = Q[b] @ K[b]^T  (raw, scale folded into softmax)
    gemm_bt<0, false, unsigned short><<<dim3(16, 16, 4), blk, 0, stream>>>(
        Q, Kb, nullptr, S, 2048, 2048, 1024,
        (long)2048 * 1024, (long)2048 * 1024, (long)2048 * 2048);
    softmax_inplace<<<dim3(NBATCH * SEQ), blk, 0, stream>>>(S);

    // attn[b] = P[b] @ V[b]  (Bt = Vt[b])
    gemm_bt<0, false, unsigned short><<<dim3(8, 16, 4), blk, 0, stream>>>(
        S, Vt, nullptr, At, 2048, 1024, 2048,
        (long)2048 * 2048, (long)1024 * 2048, (long)2048 * 1024);

    // out = attn @ Wo + bo  (fp32 store)
    gemm_bt<0, true, float><<<dim3(8, 64, 1), blk, 0, stream>>>(
        At, Wot, bo, out, 8192, 1024, 1024, 0, 0, 0);
}

// Round 4
// 343.843 us; speedup vs baseline: 1.0649x; 1.0649x over previous
//
#include <hip/hip_runtime.h>
#include <stdint.h>

#define D_MODEL 1024
#define SEQ 2048
#define NBATCH 4

typedef __attribute__((ext_vector_type(4))) float f32x4;
typedef __attribute__((ext_vector_type(8))) __bf16 bf16x8;
typedef __attribute__((ext_vector_type(4))) unsigned short u16x4;

__device__ __forceinline__ float b2f(unsigned short u) {
    union { unsigned int i; float f; } c; c.i = ((unsigned int)u) << 16; return c.f;
}
__device__ __forceinline__ unsigned short f2b(float f) {
    union { float f; unsigned int i; } c; c.f = f;
    unsigned int u = c.i;
    u += 0x7FFFu + ((u >> 16) & 1u);
    return (unsigned short)(u >> 16);
}

__device__ __forceinline__ void glds16(void* lds, const void* g) {
    __builtin_amdgcn_global_load_lds((const __attribute__((address_space(1))) void*)g,
                                     (__attribute__((address_space(3))) void*)lds,
                                     16, 0, 0);
}

// Shared GEMM core: acc[4][4] += A[128 rows @ m0] * Bt[128 rows @ n0]^T over K.
// m97 structure: global_load_lds width-16 staging, 2 barriers per K-step.
// XOR swizzle: global chunk c of row r stored at LDS chunk c ^ ((r>>1)&3)
// (applied on the global source side since glds destinations are lane-linear);
// readers fetch chunk quad ^ ((fr>>1)&3) -> 2-way banking (free) instead of 8-way.
__device__ __forceinline__ void gemm_tile(const unsigned short* __restrict__ A,
                                          const unsigned short* __restrict__ Bt,
                                          int K, int m0, int n0,
                                          f32x4 (&acc)[4][4])
{
    __shared__ alignas(16) unsigned short As[128 * 32];
    __shared__ alignas(16) unsigned short Bs[128 * 32];

    const int t    = threadIdx.x;
    const int wave = t >> 6;
    const int lane = t & 63;
    const int srow = t >> 2;                         // staging row (0..63, +64)
    const int sw   = ((t & 3) ^ ((srow >> 1) & 3)) * 8;  // swizzled src chunk

    const unsigned short* Ag = A  + (long)(m0 + srow) * K + sw;
    const unsigned short* Bg = Bt + (long)(n0 + srow) * K + sw;

    // wave-uniform LDS bases; HW writes lane i at base + i*16
    char* AsB = (char*)As + wave * 1024;
    char* BsB = (char*)Bs + wave * 1024;

    const int wm   = (wave >> 1) * 64;
    const int wn   = (wave & 1) * 64;
    const int fr   = lane & 15;
    const int quad = lane >> 4;
    const int rsw  = ((quad ^ ((fr >> 1) & 3)) & 3) * 8;  // swizzled read chunk

    for (int k0 = 0; k0 < K; k0 += 32) {
        __syncthreads();                 // all waves done reading previous tile
        glds16(AsB,        Ag + k0);
        glds16(AsB + 4096, Ag + 64 * (long)K + k0);
        glds16(BsB,        Bg + k0);
        glds16(BsB + 4096, Bg + 64 * (long)K + k0);
        __syncthreads();                 // compiler drains vmcnt(0) before barrier

        bf16x8 af[4], bfv[4];
        #pragma unroll
        for (int i = 0; i < 4; ++i)      // A frag: m = fr, k = quad*8 + j
            af[i] = *(const bf16x8*)(As + (wm + i * 16 + fr) * 32 + rsw);
        #pragma unroll
        for (int i = 0; i < 4; ++i)      // B frag: n = fr, k = quad*8 + j
            bfv[i] = *(const bf16x8*)(Bs + (wn + i * 16 + fr) * 32 + rsw);

        #pragma unroll
        for (int mi = 0; mi < 4; ++mi)
            #pragma unroll
            for (int ni = 0; ni < 4; ++ni)
                acc[mi][ni] = __builtin_amdgcn_mfma_f32_16x16x32_bf16(
                                  af[mi], bfv[ni], acc[mi][ni], 0, 0, 0);
    }
}

// Plain-store GEMM, z-batched via element strides. OutT = ushort(bf16) | float.
template<bool BIAS, typename OutT>
__global__ __launch_bounds__(256)
void gemm_bt(const unsigned short* __restrict__ A,
             const unsigned short* __restrict__ Bt,
             const float* __restrict__ bias,
             OutT* __restrict__ C,
             int N, int K, long sA, long sB, long sC)
{
    A  += (long)blockIdx.z * sA;
    Bt += (long)blockIdx.z * sB;
    C  += (long)blockIdx.z * sC;
    const int m0 = blockIdx.y * 128;
    const int n0 = blockIdx.x * 128;

    f32x4 acc[4][4] = {};
    gemm_tile(A, Bt, K, m0, n0, acc);

    const int t = threadIdx.x, wave = t >> 6, lane = t & 63;
    const int wm = (wave >> 1) * 64, wn = (wave & 1) * 64;
    const int fr = lane & 15, quad = lane >> 4;

    float bb[4] = {0.f, 0.f, 0.f, 0.f};
    if (BIAS) {
        #pragma unroll
        for (int ni = 0; ni < 4; ++ni)
            bb[ni] = bias[n0 + wn + ni * 16 + fr];
    }

    // C/D layout (HW-verified): col = lane&15, row = quad*4 + reg
    #pragma unroll
    for (int mi = 0; mi < 4; ++mi) {
        const int rowb = m0 + wm + mi * 16 + quad * 4;
        #pragma unroll
        for (int ni = 0; ni < 4; ++ni) {
            const int col = n0 + wn + ni * 16 + fr;
            f32x4 v = acc[mi][ni];
            if constexpr (sizeof(OutT) == 4) {
                #pragma unroll
                for (int r = 0; r < 4; ++r)
                    C[(long)(rowb + r) * N + col] = v[r] + bb[ni];
            } else {
                #pragma unroll
                for (int r = 0; r < 4; ++r)
                    C[(long)(rowb + r) * N + col] = (OutT)f2b(v[r] + bb[ni]);
            }
        }
    }
}

// Fused QKV projection: grid (8, 64, 3); z selects weight/bias/output.
// z==2 (V) stores transposed per batch: Vt[b][n][s], b = row>>11, s = row&2047.
__global__ __launch_bounds__(256)
void qkv_gemm(const unsigned short* __restrict__ xb,
              const unsigned short* __restrict__ Wqt,
              const unsigned short* __restrict__ Wkt,
              const unsigned short* __restrict__ Wvt,
              const float* __restrict__ bq, const float* __restrict__ bk,
              const float* __restrict__ bv,
              unsigned short* __restrict__ Q, unsigned short* __restrict__ Kb,
              unsigned short* __restrict__ Vt)
{
    const unsigned short* Bt; const float* bias; unsigned short* C; bool tstore = false;
    switch (blockIdx.z) {
        case 0:  Bt = Wqt; bias = bq; C = Q;  break;
        case 1:  Bt = Wkt; bias = bk; C = Kb; break;
        default: Bt = Wvt; bias = bv; C = Vt; tstore = true; break;
    }
    const int m0 = blockIdx.y * 128;
    const int n0 = blockIdx.x * 128;
    const int N = D_MODEL, K = D_MODEL;

    f32x4 acc[4][4] = {};
    gemm_tile(xb, Bt, K, m0, n0, acc);

    const int t = threadIdx.x, wave = t >> 6, lane = t & 63;
    const int wm = (wave >> 1) * 64, wn = (wave & 1) * 64;
    const int fr = lane & 15, quad = lane >> 4;

    float bb[4];
    #pragma unroll
    for (int ni = 0; ni < 4; ++ni)
        bb[ni] = bias[n0 + wn + ni * 16 + fr];

    #pragma unroll
    for (int mi = 0; mi < 4; ++mi) {
        const int rowb = m0 + wm + mi * 16 + quad * 4;
        #pragma unroll
        for (int ni = 0; ni < 4; ++ni) {
            const int col = n0 + wn + ni * 16 + fr;
            f32x4 v = acc[mi][ni];
            if (!tstore) {
                #pragma unroll
                for (int r = 0; r < 4; ++r)
                    C[(long)(rowb + r) * N + col] = f2b(v[r] + bb[ni]);
            } else {
                u16x4 pk;
                #pragma unroll
                for (int r = 0; r < 4; ++r)
                    pk[r] = f2b(v[r] + bb[ni]);
                unsigned short* dst = C + ((long)(rowb >> 11)) * ((long)N * SEQ)
                                        + (long)col * SEQ + (rowb & (SEQ - 1));
                *(u16x4*)dst = pk;
            }
        }
    }
}

// In-place softmax over rows of 2048 bf16 raw scores, 1/sqrt(1024) folded in.
__global__ __launch_bounds__(256)
void softmax_inplace(unsigned short* __restrict__ S)
{
    const long row = blockIdx.x;
    unsigned short* s = S + row * SEQ;
    const int t = threadIdx.x;

    u16x4 a = ((const u16x4*)s)[t];
    u16x4 b = ((const u16x4*)s)[t + 256];
    float v[8];
    #pragma unroll
    for (int i = 0; i < 4; ++i) { v[i] = b2f(a[i]); v[4 + i] = b2f(b[i]); }

    float mx = v[0];
    #pragma unroll
    for (int i = 1; i < 8; ++i) mx = fmaxf(mx, v[i]);
    #pragma unroll
    for (int off = 32; off; off >>= 1) mx = fmaxf(mx, __shfl_xor(mx, off));

    __shared__ float red[8];
    const int wv = t >> 6, ln = t & 63;
    if (ln == 0) red[wv] = mx;
    __syncthreads();
    mx = fmaxf(fmaxf(red[0], red[1]), fmaxf(red[2], red[3]));

    const float sc = 0.03125f;
    float e[8], sum = 0.f;
    #pragma unroll
    for (int i = 0; i < 8; ++i) { e[i] = __expf((v[i] - mx) * sc); sum += e[i]; }
    #pragma unroll
    for (int off = 32; off; off >>= 1) sum += __shfl_xor(sum, off);
    if (ln == 0) red[4 + wv] = sum;
    __syncthreads();
    sum = (red[4] + red[5]) + (red[6] + red[7]);
    const float inv = 1.f / sum;

    u16x4 o;
    #pragma unroll
    for (int i = 0; i < 4; ++i) o[i] = f2b(e[i] * inv);
    ((u16x4*)s)[t] = o;
    #pragma unroll
    for (int i = 0; i < 4; ++i) o[i] = f2b(e[4 + i] * inv);
    ((u16x4*)s)[t + 256] = o;
}

// Fused prep: blocks [0,8192) cast x fp32->bf16 (1024 elems each);
// blocks [8192,12288) transpose+cast the four weights (32x32 tiles).
__global__ __launch_bounds__(256)
void prep(const float* __restrict__ x, unsigned short* __restrict__ xb,
          const float* __restrict__ W0, const float* __restrict__ W1,
          const float* __restrict__ W2, const float* __restrict__ W3,
          unsigned short* __restrict__ T0, unsigned short* __restrict__ T1,
          unsigned short* __restrict__ T2, unsigned short* __restrict__ T3)
{
    const int bid = blockIdx.x;
    if (bid < 8192) {
        long i = ((long)bid * 256 + threadIdx.x) * 4;
        f32x4 v = *(const f32x4*)(x + i);
        u16x4 o;
        #pragma unroll
        for (int r = 0; r < 4; ++r) o[r] = f2b(v[r]);
        *(u16x4*)(xb + i) = o;
        return;
    }
    const int b2 = bid - 8192;
    const float* W; unsigned short* T;
    switch (b2 >> 10) {
        case 0:  W = W0; T = T0; break;
        case 1:  W = W1; T = T1; break;
        case 2:  W = W2; T = T2; break;
        default: W = W3; T = T3; break;
    }
    const int tile = b2 & 1023;
    const int bx = (tile & 31) * 32, by = (tile >> 5) * 32;
    __shared__ float buf[32][33];
    const int tx = threadIdx.x & 31, ty = threadIdx.x >> 5;
    #pragma unroll
    for (int i = 0; i < 32; i += 8)
        buf[ty + i][tx] = W[(long)(by + ty + i) * D_MODEL + bx + tx];
    __syncthreads();
    #pragma unroll
    for (int i = 0; i < 32; i += 8)
        T[(long)(bx + ty + i) * D_MODEL + by + tx] = f2b(buf[tx][ty + i]);
}

extern "C" void kernel_launch(void* const* d_in, const int* in_sizes, int n_in,
                              void* d_out, int out_size, void* d_ws, size_t ws_size,
                              hipStream_t stream)
{
    const float* x  = (const float*)d_in[0];
    const float* Wq = (const float*)d_in[1];
    const float* bq = (const float*)d_in[2];
    const float* Wk = (const float*)d_in[3];
    const float* bk = (const float*)d_in[4];
    const float* Wv = (const float*)d_in[5];
    const float* bv = (const float*)d_in[6];
    const float* Wo = (const float*)d_in[7];
    const float* bo = (const float*)d_in[8];
    float* out = (float*)d_out;

    char* ws = (char*)d_ws;
    const size_t MB = 1024ull * 1024ull;
    unsigned short* Wqt = (unsigned short*)(ws + 0 * MB);
    unsigned short* Wkt = (unsigned short*)(ws + 2 * MB);
    unsigned short* Wvt = (unsigned short*)(ws + 4 * MB);
    unsigned short* Wot = (unsigned short*)(ws + 6 * MB);
    unsigned short* xb  = (unsigned short*)(ws + 8 * MB);    // 16MB
    unsigned short* Q   = (unsigned short*)(ws + 24 * MB);   // 16MB
    unsigned short* Kb  = (unsigned short*)(ws + 40 * MB);   // 16MB
    unsigned short* Vt  = (unsigned short*)(ws + 56 * MB);   // 16MB
    unsigned short* At  = (unsigned short*)(ws + 72 * MB);   // 16MB
    unsigned short* S   = (unsigned short*)(ws + 88 * MB);   // 32MB -> 120MB

    const dim3 blk(256);

    prep<<<dim3(12288), blk, 0, stream>>>(x, xb, Wq, Wk, Wv, Wo, Wqt, Wkt, Wvt, Wot);

    qkv_gemm<<<dim3(8, 64, 3), blk, 0, stream>>>(xb, Wqt, Wkt, Wvt, bq, bk, bv, Q, Kb, Vt);

    // scores[b] = Q[b] @ K[b]^T (raw; scale folded into softmax)
    gemm_bt<false, unsigned short><<<dim3(16, 16, 4), blk, 0, stream>>>(
        Q, Kb, nullptr, S, 2048, 1024,
        (long)2048 * 1024, (long)2048 * 1024, (long)2048 * 2048);

    softmax_inplace<<<dim3(NBATCH * SEQ), blk, 0, stream>>>(S);

    // attn[b] = P[b] @ V[b]
    gemm_bt<false, unsigned short><<<dim3(8, 16, 4), blk, 0, stream>>>(
        S, Vt, nullptr, At, 1024, 2048,
        (long)2048 * 2048, (long)1024 * 2048, (long)2048 * 1024);

    // out = attn @ Wo + bo (fp32 store)
    gemm_bt<true, float><<<dim3(8, 64, 1), blk, 0, stream>>>(
        At, Wot, bo, out, 1024, 1024, 0, 0, 0);
}

// Round 5
// 317.791 us; speedup vs baseline: 1.1522x; 1.0820x over previous
//
#include <hip/hip_runtime.h>
#include <stdint.h>

#define D_MODEL 1024
#define SEQ 2048
#define NBATCH 4

typedef __attribute__((ext_vector_type(4))) float f32x4;
typedef __attribute__((ext_vector_type(8))) __bf16 bf16x8;
typedef __attribute__((ext_vector_type(4))) unsigned short u16x4;

__device__ __forceinline__ float b2f(unsigned short u) {
    union { unsigned int i; float f; } c; c.i = ((unsigned int)u) << 16; return c.f;
}
__device__ __forceinline__ unsigned short f2b(float f) {
    union { float f; unsigned int i; } c; c.f = f;
    unsigned int u = c.i;
    u += 0x7FFFu + ((u >> 16) & 1u);
    return (unsigned short)(u >> 16);
}

__device__ __forceinline__ void glds16(void* lds, const void* g) {
    __builtin_amdgcn_global_load_lds((const __attribute__((address_space(1))) void*)g,
                                     (__attribute__((address_space(3))) void*)lds,
                                     16, 0, 0);
}

// GEMM core, BK=64: acc[4][4] += A[128 rows @ m0] * Bt[128 rows @ n0]^T over K.
// 32 MFMA per barrier pair (vs 16 at BK=32) to halve the vmcnt(0)+barrier
// drains that rocprof shows as ~60% idle. LDS row = 128 B = one full bank
// cycle, so an XOR swizzle is mandatory: slot (row, sc) stores logical chunk
// sc ^ (row&7); staging permutes the *global source* chunk (glds LDS slots are
// lane-linear); readers fetch position (s*4+quad) ^ (fr&7) -> 2 lanes per
// 16-B position = 2-way banking (free, m136). K must be a multiple of 64.
__device__ __forceinline__ void gemm_tile(const unsigned short* __restrict__ A,
                                          const unsigned short* __restrict__ Bt,
                                          int K, int m0, int n0,
                                          f32x4 (&acc)[4][4])
{
    __shared__ alignas(16) unsigned short As[128 * 64];
    __shared__ alignas(16) unsigned short Bs[128 * 64];

    const int t    = threadIdx.x;
    const int wave = t >> 6;
    const int lane = t & 63;
    const int srow = t >> 3;                        // row within j-group (0..31)
    const int sch  = ((t & 7) ^ (srow & 7)) * 8;    // permuted source chunk (elems)

    const unsigned short* Ag = A  + (long)(m0 + srow) * K + sch;
    const unsigned short* Bg = Bt + (long)(n0 + srow) * K + sch;

    // j-group j covers rows j*32..j*32+31, LDS bytes j*4096 + t*16.
    // glds needs the wave-uniform base: j*4096 + wave*1024 (+ lane*16 by HW).
    char* AsB = (char*)As + wave * 1024;
    char* BsB = (char*)Bs + wave * 1024;

    const int wm   = (wave >> 1) * 64;
    const int wn   = (wave & 1) * 64;
    const int fr   = lane & 15;
    const int quad = lane >> 4;
    const int rp0  = ((quad    ) ^ (fr & 7)) * 16;  // slice 0 byte offset in row
    const int rp1  = ((4 + quad) ^ (fr & 7)) * 16;  // slice 1

    for (int k0 = 0; k0 < K; k0 += 64) {
        __syncthreads();                  // all waves done reading previous tile
        #pragma unroll
        for (int j = 0; j < 4; ++j) {
            glds16(AsB + j * 4096, Ag + (long)(j * 32) * K + k0);
            glds16(BsB + j * 4096, Bg + (long)(j * 32) * K + k0);
        }
        __syncthreads();                  // vmcnt(0) drained before barrier

        #pragma unroll
        for (int s = 0; s < 2; ++s) {
            const int ro = s ? rp1 : rp0;
            bf16x8 af[4], bfv[4];
            #pragma unroll
            for (int i = 0; i < 4; ++i)   // A frag: m = fr, k = s*32 + quad*8 + j
                af[i] = *(const bf16x8*)((const char*)As + (wm + i * 16 + fr) * 128 + ro);
            #pragma unroll
            for (int i = 0; i < 4; ++i)   // B frag: n = fr, same k
                bfv[i] = *(const bf16x8*)((const char*)Bs + (wn + i * 16 + fr) * 128 + ro);

            #pragma unroll
            for (int mi = 0; mi < 4; ++mi)
                #pragma unroll
                for (int ni = 0; ni < 4; ++ni)
                    acc[mi][ni] = __builtin_amdgcn_mfma_f32_16x16x32_bf16(
                                      af[mi], bfv[ni], acc[mi][ni], 0, 0, 0);
        }
    }
}

// Plain-store GEMM, z-batched via element strides. OutT = ushort(bf16) | float.
template<bool BIAS, typename OutT>
__global__ __launch_bounds__(256)
void gemm_bt(const unsigned short* __restrict__ A,
             const unsigned short* __restrict__ Bt,
             const float* __restrict__ bias,
             OutT* __restrict__ C,
             int N, int K, long sA, long sB, long sC)
{
    A  += (long)blockIdx.z * sA;
    Bt += (long)blockIdx.z * sB;
    C  += (long)blockIdx.z * sC;
    const int m0 = blockIdx.y * 128;
    const int n0 = blockIdx.x * 128;

    f32x4 acc[4][4] = {};
    gemm_tile(A, Bt, K, m0, n0, acc);

    const int t = threadIdx.x, wave = t >> 6, lane = t & 63;
    const int wm = (wave >> 1) * 64, wn = (wave & 1) * 64;
    const int fr = lane & 15, quad = lane >> 4;

    float bb[4] = {0.f, 0.f, 0.f, 0.f};
    if (BIAS) {
        #pragma unroll
        for (int ni = 0; ni < 4; ++ni)
            bb[ni] = bias[n0 + wn + ni * 16 + fr];
    }

    // C/D layout (HW-verified): col = lane&15, row = quad*4 + reg
    #pragma unroll
    for (int mi = 0; mi < 4; ++mi) {
        const int rowb = m0 + wm + mi * 16 + quad * 4;
        #pragma unroll
        for (int ni = 0; ni < 4; ++ni) {
            const int col = n0 + wn + ni * 16 + fr;
            f32x4 v = acc[mi][ni];
            if constexpr (sizeof(OutT) == 4) {
                #pragma unroll
                for (int r = 0; r < 4; ++r)
                    C[(long)(rowb + r) * N + col] = v[r] + bb[ni];
            } else {
                #pragma unroll
                for (int r = 0; r < 4; ++r)
                    C[(long)(rowb + r) * N + col] = (OutT)f2b(v[r] + bb[ni]);
            }
        }
    }
}

// Fused QKV projection: grid (8, 64, 3); z selects weight/bias/output.
// z==2 (V) stores transposed per batch: Vt[b][n][s], b = row>>11, s = row&2047.
__global__ __launch_bounds__(256)
void qkv_gemm(const unsigned short* __restrict__ xb,
              const unsigned short* __restrict__ Wqt,
              const unsigned short* __restrict__ Wkt,
              const unsigned short* __restrict__ Wvt,
              const float* __restrict__ bq, const float* __restrict__ bk,
              const float* __restrict__ bv,
              unsigned short* __restrict__ Q, unsigned short* __restrict__ Kb,
              unsigned short* __restrict__ Vt)
{
    const unsigned short* Bt; const float* bias; unsigned short* C; bool tstore = false;
    switch (blockIdx.z) {
        case 0:  Bt = Wqt; bias = bq; C = Q;  break;
        case 1:  Bt = Wkt; bias = bk; C = Kb; break;
        default: Bt = Wvt; bias = bv; C = Vt; tstore = true; break;
    }
    const int m0 = blockIdx.y * 128;
    const int n0 = blockIdx.x * 128;
    const int N = D_MODEL, K = D_MODEL;

    f32x4 acc[4][4] = {};
    gemm_tile(xb, Bt, K, m0, n0, acc);

    const int t = threadIdx.x, wave = t >> 6, lane = t & 63;
    const int wm = (wave >> 1) * 64, wn = (wave & 1) * 64;
    const int fr = lane & 15, quad = lane >> 4;

    float bb[4];
    #pragma unroll
    for (int ni = 0; ni < 4; ++ni)
        bb[ni] = bias[n0 + wn + ni * 16 + fr];

    #pragma unroll
    for (int mi = 0; mi < 4; ++mi) {
        const int rowb = m0 + wm + mi * 16 + quad * 4;
        #pragma unroll
        for (int ni = 0; ni < 4; ++ni) {
            const int col = n0 + wn + ni * 16 + fr;
            f32x4 v = acc[mi][ni];
            if (!tstore) {
                #pragma unroll
                for (int r = 0; r < 4; ++r)
                    C[(long)(rowb + r) * N + col] = f2b(v[r] + bb[ni]);
            } else {
                u16x4 pk;
                #pragma unroll
                for (int r = 0; r < 4; ++r)
                    pk[r] = f2b(v[r] + bb[ni]);
                unsigned short* dst = C + ((long)(rowb >> 11)) * ((long)N * SEQ)
                                        + (long)col * SEQ + (rowb & (SEQ - 1));
                *(u16x4*)dst = pk;
            }
        }
    }
}

// In-place softmax over rows of 2048 bf16 raw scores, 1/sqrt(1024) folded in.
__global__ __launch_bounds__(256)
void softmax_inplace(unsigned short* __restrict__ S)
{
    const long row = blockIdx.x;
    unsigned short* s = S + row * SEQ;
    const int t = threadIdx.x;

    u16x4 a = ((const u16x4*)s)[t];
    u16x4 b = ((const u16x4*)s)[t + 256];
    float v[8];
    #pragma unroll
    for (int i = 0; i < 4; ++i) { v[i] = b2f(a[i]); v[4 + i] = b2f(b[i]); }

    float mx = v[0];
    #pragma unroll
    for (int i = 1; i < 8; ++i) mx = fmaxf(mx, v[i]);
    #pragma unroll
    for (int off = 32; off; off >>= 1) mx = fmaxf(mx, __shfl_xor(mx, off));

    __shared__ float red[8];
    const int wv = t >> 6, ln = t & 63;
    if (ln == 0) red[wv] = mx;
    __syncthreads();
    mx = fmaxf(fmaxf(red[0], red[1]), fmaxf(red[2], red[3]));

    const float sc = 0.03125f;
    float e[8], sum = 0.f;
    #pragma unroll
    for (int i = 0; i < 8; ++i) { e[i] = __expf((v[i] - mx) * sc); sum += e[i]; }
    #pragma unroll
    for (int off = 32; off; off >>= 1) sum += __shfl_xor(sum, off);
    if (ln == 0) red[4 + wv] = sum;
    __syncthreads();
    sum = (red[4] + red[5]) + (red[6] + red[7]);
    const float inv = 1.f / sum;

    u16x4 o;
    #pragma unroll
    for (int i = 0; i < 4; ++i) o[i] = f2b(e[i] * inv);
    ((u16x4*)s)[t] = o;
    #pragma unroll
    for (int i = 0; i < 4; ++i) o[i] = f2b(e[4 + i] * inv);
    ((u16x4*)s)[t + 256] = o;
}

// Fused prep: blocks [0,8192) cast x fp32->bf16 (1024 elems each);
// blocks [8192,12288) transpose+cast the four weights (32x32 tiles).
__global__ __launch_bounds__(256)
void prep(const float* __restrict__ x, unsigned short* __restrict__ xb,
          const float* __restrict__ W0, const float* __restrict__ W1,
          const float* __restrict__ W2, const float* __restrict__ W3,
          unsigned short* __restrict__ T0, unsigned short* __restrict__ T1,
          unsigned short* __restrict__ T2, unsigned short* __restrict__ T3)
{
    const int bid = blockIdx.x;
    if (bid < 8192) {
        long i = ((long)bid * 256 + threadIdx.x) * 4;
        f32x4 v = *(const f32x4*)(x + i);
        u16x4 o;
        #pragma unroll
        for (int r = 0; r < 4; ++r) o[r] = f2b(v[r]);
        *(u16x4*)(xb + i) = o;
        return;
    }
    const int b2 = bid - 8192;
    const float* W; unsigned short* T;
    switch (b2 >> 10) {
        case 0:  W = W0; T = T0; break;
        case 1:  W = W1; T = T1; break;
        case 2:  W = W2; T = T2; break;
        default: W = W3; T = T3; break;
    }
    const int tile = b2 & 1023;
    const int bx = (tile & 31) * 32, by = (tile >> 5) * 32;
    __shared__ float buf[32][33];
    const int tx = threadIdx.x & 31, ty = threadIdx.x >> 5;
    #pragma unroll
    for (int i = 0; i < 32; i += 8)
        buf[ty + i][tx] = W[(long)(by + ty + i) * D_MODEL + bx + tx];
    __syncthreads();
    #pragma unroll
    for (int i = 0; i < 32; i += 8)
        T[(long)(bx + ty + i) * D_MODEL + by + tx] = f2b(buf[tx][ty + i]);
}

extern "C" void kernel_launch(void* const* d_in, const int* in_sizes, int n_in,
                              void* d_out, int out_size, void* d_ws, size_t ws_size,
                              hipStream_t stream)
{
    const float* x  = (const float*)d_in[0];
    const float* Wq = (const float*)d_in[1];
    const float* bq = (const float*)d_in[2];
    const float* Wk = (const float*)d_in[3];
    const float* bk = (const float*)d_in[4];
    const float* Wv = (const float*)d_in[5];
    const float* bv = (const float*)d_in[6];
    const float* Wo = (const float*)d_in[7];
    const float* bo = (const float*)d_in[8];
    float* out = (float*)d_out;

    char* ws = (char*)d_ws;
    const size_t MB = 1024ull * 1024ull;
    unsigned short* Wqt = (unsigned short*)(ws + 0 * MB);
    unsigned short* Wkt = (unsigned short*)(ws + 2 * MB);
    unsigned short* Wvt = (unsigned short*)(ws + 4 * MB);
    unsigned short* Wot = (unsigned short*)(ws + 6 * MB);
    unsigned short* xb  = (unsigned short*)(ws + 8 * MB);    // 16MB
    unsigned short* Q   = (unsigned short*)(ws + 24 * MB);   // 16MB
    unsigned short* Kb  = (unsigned short*)(ws + 40 * MB);   // 16MB
    unsigned short* Vt  = (unsigned short*)(ws + 56 * MB);   // 16MB
    unsigned short* At  = (unsigned short*)(ws + 72 * MB);   // 16MB
    unsigned short* S   = (unsigned short*)(ws + 88 * MB);   // 32MB -> 120MB

    const dim3 blk(256);

    prep<<<dim3(12288), blk, 0, stream>>>(x, xb, Wq, Wk, Wv, Wo, Wqt, Wkt, Wvt, Wot);

    qkv_gemm<<<dim3(8, 64, 3), blk, 0, stream>>>(xb, Wqt, Wkt, Wvt, bq, bk, bv, Q, Kb, Vt);

    // scores[b] = Q[b] @ K[b]^T (raw; scale folded into softmax)
    gemm_bt<false, unsigned short><<<dim3(16, 16, 4), blk, 0, stream>>>(
        Q, Kb, nullptr, S, 2048, 1024,
        (long)2048 * 1024, (long)2048 * 1024, (long)2048 * 2048);

    softmax_inplace<<<dim3(NBATCH * SEQ), blk, 0, stream>>>(S);

    // attn[b] = P[b] @ V[b]
    gemm_bt<false, unsigned short><<<dim3(8, 16, 4), blk, 0, stream>>>(
        S, Vt, nullptr, At, 1024, 2048,
        (long)2048 * 2048, (long)1024 * 2048, (long)2048 * 1024);

    // out = attn @ Wo + bo (fp32 store)
    gemm_bt<true, float><<<dim3(8, 64, 1), blk, 0, stream>>>(
        At, Wot, bo, out, 1024, 1024, 0, 0, 0);
}

// Round 6
// 291.473 us; speedup vs baseline: 1.2563x; 1.0903x over previous
//
#include <hip/hip_runtime.h>
#include <stdint.h>

#define D_MODEL 1024
#define SEQ 2048
#define NBATCH 4

typedef __attribute__((ext_vector_type(4))) float f32x4;
typedef __attribute__((ext_vector_type(8))) __bf16 bf16x8;
typedef __attribute__((ext_vector_type(4))) unsigned short u16x4;

__device__ __forceinline__ float b2f(unsigned short u) {
    union { unsigned int i; float f; } c; c.i = ((unsigned int)u) << 16; return c.f;
}
__device__ __forceinline__ unsigned short f2b(float f) {
    union { float f; unsigned int i; } c; c.f = f;
    unsigned int u = c.i;
    u += 0x7FFFu + ((u >> 16) & 1u);
    return (unsigned short)(u >> 16);
}

__device__ __forceinline__ void glds16(void* lds, const void* g) {
    __builtin_amdgcn_global_load_lds((const __attribute__((address_space(1))) void*)g,
                                     (__attribute__((address_space(3))) void*)lds,
                                     16, 0, 0);
}

// XCD-aware tile remap. HW dispatches blocks round-robin over 8 XCDs
// (xcd = bid % 8); default x-fastest order makes every XCD's L2 pull the
// whole A matrix (qkv FETCH showed 204 MB vs 22 MB ideal). Remap so each
// XCD owns a contiguous y-band of height H = gy/8 across all x,z:
// per-XCD read set shrinks to its A-band + shared B. Pure permutation.
__device__ __forceinline__ void xcd_map(int& xx, int& yy, int& zz)
{
    const int gx = gridDim.x, gy = gridDim.y;
    int bid = blockIdx.x + gx * (blockIdx.y + gy * blockIdx.z);
    const int H = gy >> 3;              // all our grids have gy in {16,64}
    const int xcd = bid & 7;
    int slot = bid >> 3;
    yy = xcd * H + (slot % H);
    slot /= H;
    xx = slot % gx;
    zz = slot / gx;
}

// GEMM core, BK=64: acc[4][4] += A[128 rows @ m0] * Bt[128 rows @ n0]^T over K.
// m97-style glds staging; XOR swizzle (slot (row,sc) holds chunk sc^(row&7),
// permuted on the global-source side; readers fetch (s*4+quad)^(fr&7)) ->
// 2-way banking (free). K multiple of 64.
__device__ __forceinline__ void gemm_tile(const unsigned short* __restrict__ A,
                                          const unsigned short* __restrict__ Bt,
                                          int K, int m0, int n0,
                                          f32x4 (&acc)[4][4])
{
    __shared__ alignas(16) unsigned short As[128 * 64];
    __shared__ alignas(16) unsigned short Bs[128 * 64];

    const int t    = threadIdx.x;
    const int wave = t >> 6;
    const int lane = t & 63;
    const int srow = t >> 3;                        // row within j-group (0..31)
    const int sch  = ((t & 7) ^ (srow & 7)) * 8;    // permuted source chunk (elems)

    const unsigned short* Ag = A  + (long)(m0 + srow) * K + sch;
    const unsigned short* Bg = Bt + (long)(n0 + srow) * K + sch;

    char* AsB = (char*)As + wave * 1024;            // wave-uniform glds base
    char* BsB = (char*)Bs + wave * 1024;

    const int wm   = (wave >> 1) * 64;
    const int wn   = (wave & 1) * 64;
    const int fr   = lane & 15;
    const int quad = lane >> 4;
    const int rp0  = ((quad    ) ^ (fr & 7)) * 16;
    const int rp1  = ((4 + quad) ^ (fr & 7)) * 16;

    for (int k0 = 0; k0 < K; k0 += 64) {
        __syncthreads();
        #pragma unroll
        for (int j = 0; j < 4; ++j) {
            glds16(AsB + j * 4096, Ag + (long)(j * 32) * K + k0);
            glds16(BsB + j * 4096, Bg + (long)(j * 32) * K + k0);
        }
        __syncthreads();

        #pragma unroll
        for (int s = 0; s < 2; ++s) {
            const int ro = s ? rp1 : rp0;
            bf16x8 af[4], bfv[4];
            #pragma unroll
            for (int i = 0; i < 4; ++i)
                af[i] = *(const bf16x8*)((const char*)As + (wm + i * 16 + fr) * 128 + ro);
            #pragma unroll
            for (int i = 0; i < 4; ++i)
                bfv[i] = *(const bf16x8*)((const char*)Bs + (wn + i * 16 + fr) * 128 + ro);

            #pragma unroll
            for (int mi = 0; mi < 4; ++mi)
                #pragma unroll
                for (int ni = 0; ni < 4; ++ni)
                    acc[mi][ni] = __builtin_amdgcn_mfma_f32_16x16x32_bf16(
                                      af[mi], bfv[ni], acc[mi][ni], 0, 0, 0);
        }
    }
}

// Plain-store GEMM, z-batched via element strides. OutT = ushort(bf16) | float.
template<bool BIAS, typename OutT>
__global__ __launch_bounds__(256)
void gemm_bt(const unsigned short* __restrict__ A,
             const unsigned short* __restrict__ Bt,
             const float* __restrict__ bias,
             OutT* __restrict__ C,
             int N, int K, long sA, long sB, long sC)
{
    int xx, yy, zz;
    xcd_map(xx, yy, zz);
    A  += (long)zz * sA;
    Bt += (long)zz * sB;
    C  += (long)zz * sC;
    const int m0 = yy * 128;
    const int n0 = xx * 128;

    f32x4 acc[4][4] = {};
    gemm_tile(A, Bt, K, m0, n0, acc);

    const int t = threadIdx.x, wave = t >> 6, lane = t & 63;
    const int wm = (wave >> 1) * 64, wn = (wave & 1) * 64;
    const int fr = lane & 15, quad = lane >> 4;

    float bb[4] = {0.f, 0.f, 0.f, 0.f};
    if (BIAS) {
        #pragma unroll
        for (int ni = 0; ni < 4; ++ni)
            bb[ni] = bias[n0 + wn + ni * 16 + fr];
    }

    // C/D layout (HW-verified): col = lane&15, row = quad*4 + reg
    #pragma unroll
    for (int mi = 0; mi < 4; ++mi) {
        const int rowb = m0 + wm + mi * 16 + quad * 4;
        #pragma unroll
        for (int ni = 0; ni < 4; ++ni) {
            const int col = n0 + wn + ni * 16 + fr;
            f32x4 v = acc[mi][ni];
            if constexpr (sizeof(OutT) == 4) {
                #pragma unroll
                for (int r = 0; r < 4; ++r)
                    C[(long)(rowb + r) * N + col] = v[r] + bb[ni];
            } else {
                #pragma unroll
                for (int r = 0; r < 4; ++r)
                    C[(long)(rowb + r) * N + col] = (OutT)f2b(v[r] + bb[ni]);
            }
        }
    }
}

// Fused QKV projection: grid (8, 64, 3); remapped z selects weight/bias/output.
// V (z==2) stores transposed per batch: Vt[b][n][s], b = row>>11, s = row&2047.
__global__ __launch_bounds__(256)
void qkv_gemm(const unsigned short* __restrict__ xb,
              const unsigned short* __restrict__ Wqt,
              const unsigned short* __restrict__ Wkt,
              const unsigned short* __restrict__ Wvt,
              const float* __restrict__ bq, const float* __restrict__ bk,
              const float* __restrict__ bv,
              unsigned short* __restrict__ Q, unsigned short* __restrict__ Kb,
              unsigned short* __restrict__ Vt)
{
    int xx, yy, zz;
    xcd_map(xx, yy, zz);

    const unsigned short* Bt; const float* bias; unsigned short* C; bool tstore = false;
    switch (zz) {
        case 0:  Bt = Wqt; bias = bq; C = Q;  break;
        case 1:  Bt = Wkt; bias = bk; C = Kb; break;
        default: Bt = Wvt; bias = bv; C = Vt; tstore = true; break;
    }
    const int m0 = yy * 128;
    const int n0 = xx * 128;
    const int N = D_MODEL, K = D_MODEL;

    f32x4 acc[4][4] = {};
    gemm_tile(xb, Bt, K, m0, n0, acc);

    const int t = threadIdx.x, wave = t >> 6, lane = t & 63;
    const int wm = (wave >> 1) * 64, wn = (wave & 1) * 64;
    const int fr = lane & 15, quad = lane >> 4;

    float bb[4];
    #pragma unroll
    for (int ni = 0; ni < 4; ++ni)
        bb[ni] = bias[n0 + wn + ni * 16 + fr];

    #pragma unroll
    for (int mi = 0; mi < 4; ++mi) {
        const int rowb = m0 + wm + mi * 16 + quad * 4;
        #pragma unroll
        for (int ni = 0; ni < 4; ++ni) {
            const int col = n0 + wn + ni * 16 + fr;
            f32x4 v = acc[mi][ni];
            if (!tstore) {
                #pragma unroll
                for (int r = 0; r < 4; ++r)
                    C[(long)(rowb + r) * N + col] = f2b(v[r] + bb[ni]);
            } else {
                u16x4 pk;
                #pragma unroll
                for (int r = 0; r < 4; ++r)
                    pk[r] = f2b(v[r] + bb[ni]);
                unsigned short* dst = C + ((long)(rowb >> 11)) * ((long)N * SEQ)
                                        + (long)col * SEQ + (rowb & (SEQ - 1));
                *(u16x4*)dst = pk;
            }
        }
    }
}

// In-place softmax over rows of 2048 bf16 raw scores, 1/sqrt(1024) folded in.
__global__ __launch_bounds__(256)
void softmax_inplace(unsigned short* __restrict__ S)
{
    const long row = blockIdx.x;
    unsigned short* s = S + row * SEQ;
    const int t = threadIdx.x;

    u16x4 a = ((const u16x4*)s)[t];
    u16x4 b = ((const u16x4*)s)[t + 256];
    float v[8];
    #pragma unroll
    for (int i = 0; i < 4; ++i) { v[i] = b2f(a[i]); v[4 + i] = b2f(b[i]); }

    float mx = v[0];
    #pragma unroll
    for (int i = 1; i < 8; ++i) mx = fmaxf(mx, v[i]);
    #pragma unroll
    for (int off = 32; off; off >>= 1) mx = fmaxf(mx, __shfl_xor(mx, off));

    __shared__ float red[8];
    const int wv = t >> 6, ln = t & 63;
    if (ln == 0) red[wv] = mx;
    __syncthreads();
    mx = fmaxf(fmaxf(red[0], red[1]), fmaxf(red[2], red[3]));

    const float sc = 0.03125f;
    float e[8], sum = 0.f;
    #pragma unroll
    for (int i = 0; i < 8; ++i) { e[i] = __expf((v[i] - mx) * sc); sum += e[i]; }
    #pragma unroll
    for (int off = 32; off; off >>= 1) sum += __shfl_xor(sum, off);
    if (ln == 0) red[4 + wv] = sum;
    __syncthreads();
    sum = (red[4] + red[5]) + (red[6] + red[7]);
    const float inv = 1.f / sum;

    u16x4 o;
    #pragma unroll
    for (int i = 0; i < 4; ++i) o[i] = f2b(e[i] * inv);
    ((u16x4*)s)[t] = o;
    #pragma unroll
    for (int i = 0; i < 4; ++i) o[i] = f2b(e[4 + i] * inv);
    ((u16x4*)s)[t + 256] = o;
}

// Fused prep: blocks [0,8192) cast x fp32->bf16 (1024 elems each);
// blocks [8192,12288) transpose+cast the four weights (32x32 tiles).
__global__ __launch_bounds__(256)
void prep(const float* __restrict__ x, unsigned short* __restrict__ xb,
          const float* __restrict__ W0, const float* __restrict__ W1,
          const float* __restrict__ W2, const float* __restrict__ W3,
          unsigned short* __restrict__ T0, unsigned short* __restrict__ T1,
          unsigned short* __restrict__ T2, unsigned short* __restrict__ T3)
{
    const int bid = blockIdx.x;
    if (bid < 8192) {
        long i = ((long)bid * 256 + threadIdx.x) * 4;
        f32x4 v = *(const f32x4*)(x + i);
        u16x4 o;
        #pragma unroll
        for (int r = 0; r < 4; ++r) o[r] = f2b(v[r]);
        *(u16x4*)(xb + i) = o;
        return;
    }
    const int b2 = bid - 8192;
    const float* W; unsigned short* T;
    switch (b2 >> 10) {
        case 0:  W = W0; T = T0; break;
        case 1:  W = W1; T = T1; break;
        case 2:  W = W2; T = T2; break;
        default: W = W3; T = T3; break;
    }
    const int tile = b2 & 1023;
    const int bx = (tile & 31) * 32, by = (tile >> 5) * 32;
    __shared__ float buf[32][33];
    const int tx = threadIdx.x & 31, ty = threadIdx.x >> 5;
    #pragma unroll
    for (int i = 0; i < 32; i += 8)
        buf[ty + i][tx] = W[(long)(by + ty + i) * D_MODEL + bx + tx];
    __syncthreads();
    #pragma unroll
    for (int i = 0; i < 32; i += 8)
        T[(long)(bx + ty + i) * D_MODEL + by + tx] = f2b(buf[tx][ty + i]);
}

extern "C" void kernel_launch(void* const* d_in, const int* in_sizes, int n_in,
                              void* d_out, int out_size, void* d_ws, size_t ws_size,
                              hipStream_t stream)
{
    const float* x  = (const float*)d_in[0];
    const float* Wq = (const float*)d_in[1];
    const float* bq = (const float*)d_in[2];
    const float* Wk = (const float*)d_in[3];
    const float* bk = (const float*)d_in[4];
    const float* Wv = (const float*)d_in[5];
    const float* bv = (const float*)d_in[6];
    const float* Wo = (const float*)d_in[7];
    const float* bo = (const float*)d_in[8];
    float* out = (float*)d_out;

    char* ws = (char*)d_ws;
    const size_t MB = 1024ull * 1024ull;
    unsigned short* Wqt = (unsigned short*)(ws + 0 * MB);
    unsigned short* Wkt = (unsigned short*)(ws + 2 * MB);
    unsigned short* Wvt = (unsigned short*)(ws + 4 * MB);
    unsigned short* Wot = (unsigned short*)(ws + 6 * MB);
    unsigned short* xb  = (unsigned short*)(ws + 8 * MB);    // 16MB
    unsigned short* Q   = (unsigned short*)(ws + 24 * MB);   // 16MB
    unsigned short* Kb  = (unsigned short*)(ws + 40 * MB);   // 16MB
    unsigned short* Vt  = (unsigned short*)(ws + 56 * MB);   // 16MB
    unsigned short* At  = (unsigned short*)(ws + 72 * MB);   // 16MB
    unsigned short* S   = (unsigned short*)(ws + 88 * MB);   // 32MB -> 120MB

    const dim3 blk(256);

    prep<<<dim3(12288), blk, 0, stream>>>(x, xb, Wq, Wk, Wv, Wo, Wqt, Wkt, Wvt, Wot);

    qkv_gemm<<<dim3(8, 64, 3), blk, 0, stream>>>(xb, Wqt, Wkt, Wvt, bq, bk, bv, Q, Kb, Vt);

    // scores[b] = Q[b] @ K[b]^T (raw; scale folded into softmax)
    gemm_bt<false, unsigned short><<<dim3(16, 16, 4), blk, 0, stream>>>(
        Q, Kb, nullptr, S, 2048, 1024,
        (long)2048 * 1024, (long)2048 * 1024, (long)2048 * 2048);

    softmax_inplace<<<dim3(NBATCH * SEQ), blk, 0, stream>>>(S);

    // attn[b] = P[b] @ V[b]
    gemm_bt<false, unsigned short><<<dim3(8, 16, 4), blk, 0, stream>>>(
        S, Vt, nullptr, At, 1024, 2048,
        (long)2048 * 2048, (long)1024 * 2048, (long)2048 * 1024);

    // out = attn @ Wo + bo (fp32 store)
    gemm_bt<true, float><<<dim3(8, 64, 1), blk, 0, stream>>>(
        At, Wot, bo, out, 1024, 1024, 0, 0, 0);
}